// Round 5
// baseline (378.564 us; speedup 1.0000x reference)
//
#include <hip/hip_runtime.h>
#include <hip/hip_bf16.h>

#define B_   8
#define C_   128
#define H_   96
#define W_   96
#define HP_  98            // padded H/W
#define HO_  48
#define N_   2304          // HO_*HO_
#define K_CONV 1152        // C_*9
#define PLANE_IN  9216     // H_*W_
#define TOT_OUT (B_*C_*N_)

typedef __attribute__((ext_vector_type(8))) short          s16x8;
typedef __attribute__((ext_vector_type(8))) unsigned short u16x8;
typedef __attribute__((ext_vector_type(4))) unsigned short u16x4;
typedef __attribute__((ext_vector_type(4))) float          f32x4;

// XOR-swizzled byte offset for [row][32k] bf16 tiles (64 B rows, 16 B granules)
#define SW(row, q) (((row) << 6) + ((((q) ^ (((row) >> 1) & 3))) << 4))

__device__ __forceinline__ ushort f2bf(float f) {
  __hip_bfloat16 h = __float2bfloat16(f);
  return *reinterpret_cast<ushort*>(&h);
}
__device__ __forceinline__ float bf2f(ushort u) {
  return __uint_as_float(((unsigned int)u) << 16);
}

__device__ __forceinline__ float block_reduce_sum_256(float v) {
  #pragma unroll
  for (int o = 32; o > 0; o >>= 1) v += __shfl_down(v, o, 64);
  __shared__ float r[4];
  int lane = threadIdx.x & 63, wv = threadIdx.x >> 6;
  if (lane == 0) r[wv] = v;
  __syncthreads();
  float s = 0.f;
  if (threadIdx.x == 0) s = r[0] + r[1] + r[2] + r[3];
  __syncthreads();
  return s;  // valid on thread 0 only
}

// ---------------- BN param prep ---------------------------------------------
__global__ void k_prep(const float* __restrict__ w, const float* __restrict__ bb,
                       const float* __restrict__ m, const float* __restrict__ v,
                       float* __restrict__ inv, float* __restrict__ beta) {
  int c = threadIdx.x;
  if (c < C_) {
    float iv = w[c] / sqrtf(v[c] + 1e-5f);
    inv[c] = iv;
    beta[c] = bb[c] - m[c] * iv;
  }
}

// ---------------- conv weights fp32 OIHW -> bf16 [co][(kh*3+kw)*128+ci] -----
__global__ __launch_bounds__(256) void k_prep_w(const float* __restrict__ w,
                                                ushort* __restrict__ wb) {
  int id = blockIdx.x * 256 + threadIdx.x;
  if (id >= C_ * K_CONV) return;
  int co = id / K_CONV, rem = id - co * K_CONV;
  int tap = rem >> 7, ci = rem & 127;
  wb[id] = f2bf(w[co * K_CONV + ci * 9 + tap]);
}

// ---------------- x -> 3x padded NHWC bf16 y (BN+ReLU fused) ----------------
__global__ __launch_bounds__(256) void k_prep_y(const float* __restrict__ x,
                                                const float* __restrict__ pinv,
                                                const float* __restrict__ pbeta,
                                                ushort* __restrict__ y0,
                                                ushort* __restrict__ y1,
                                                ushort* __restrict__ y2) {
  const int h1 = blockIdx.x, b = blockIdx.y, t = threadIdx.x;
  ushort* ys[3] = {y0 + (size_t)b * HP_ * HP_ * C_,
                   y1 + (size_t)b * HP_ * HP_ * C_,
                   y2 + (size_t)b * HP_ * HP_ * C_};
  u16x8 zer = (u16x8)0;
  if (h1 == 0 || h1 == HP_ - 1) {
    for (int p = 0; p < 3; ++p)
      for (int g = t; g < HP_ * C_ / 8; g += 256)
        *(u16x8*)(ys[p] + (size_t)h1 * HP_ * C_ + g * 8) = zer;
    return;
  }
  __shared__ float xs[128][97];
  const int h = h1 - 1;
  const float* xb = x + (size_t)b * C_ * PLANE_IN + h * W_;
  for (int id = t; id < 128 * 24; id += 256) {
    int ci = id / 24, w4 = id - ci * 24;
    float4 v = *(const float4*)(xb + (size_t)ci * PLANE_IN + w4 * 4);
    xs[ci][w4 * 4 + 0] = v.x; xs[ci][w4 * 4 + 1] = v.y;
    xs[ci][w4 * 4 + 2] = v.z; xs[ci][w4 * 4 + 3] = v.w;
  }
  __syncthreads();
  // edge pixels w1=0, w1=97
  if (t < 32) {
    int side = t >> 4, cg = t & 15;
    for (int p = 0; p < 3; ++p)
      *(u16x8*)(ys[p] + ((size_t)h1 * HP_ + (side ? HP_ - 1 : 0)) * C_ + cg * 8) = zer;
  }
  for (int p = 0; p < 3; ++p) {
    const float* inv = pinv + p * 128;
    const float* bet = pbeta + p * 128;
    for (int g = t; g < 96 * 16; g += 256) {
      int wdx = g >> 4, cg = g & 15;
      u16x8 o;
      #pragma unroll
      for (int k = 0; k < 8; ++k) {
        int ci = cg * 8 + k;
        o[k] = f2bf(fmaxf(xs[ci][wdx] * inv[ci] + bet[ci], 0.f));
      }
      *(u16x8*)(ys[p] + ((size_t)h1 * HP_ + (wdx + 1)) * C_ + cg * 8) = o;
    }
  }
}

// ---------------- wx = relu(mean_{hw} x) ------------------------------------
__global__ __launch_bounds__(256) void k_meanx(const float* __restrict__ x,
                                               float* __restrict__ wcat) {
  int bc = blockIdx.x;
  const float* p = x + (size_t)bc * PLANE_IN;
  float s = 0.f;
  for (int i = threadIdx.x; i < PLANE_IN; i += 256) s += p[i];
  s = block_reduce_sum_256(s);
  if (threadIdx.x == 0) {
    int b = bc >> 7, c = bc & 127;
    wcat[b * 256 + c] = fmaxf(s * (1.f / PLANE_IN), 0.f);
  }
}

// ---------------- MFMA implicit-GEMM conv: M=128co x N=64pos x K=1152 -------
// mode 0: out[b][n][c] bf16 (f,g)   mode 1: out[b][c][n] bf16 (h)
__global__ __launch_bounds__(256) void k_conv(const ushort* __restrict__ y_all,
                                              const ushort* __restrict__ wb,
                                              const float* __restrict__ bias,
                                              ushort* __restrict__ out, int mode) {
  __shared__ __align__(16) char smem[16384];
  char* As = smem;          // 128 rows x 64 B (swizzled)
  char* Bs = smem + 8192;   // 64 rows x 64 B (swizzled)
  const int b = blockIdx.z, n0 = blockIdx.x * 64;
  const int t = threadIdx.x, l = t & 63, w = t >> 6;
  const ushort* yb = y_all + (size_t)b * HP_ * HP_ * C_;
  const int pos = t >> 2, q = t & 3;         // B staging assignment
  const int n_glob = n0 + pos;
  const int oh = n_glob / HO_, ow = n_glob - oh * HO_;
  const int mh = (w & 1) * 64, nh = (w >> 1) * 32;
  f32x4 acc[4][2];
  #pragma unroll
  for (int i = 0; i < 4; ++i)
    #pragma unroll
    for (int j = 0; j < 2; ++j) acc[i][j] = (f32x4)0.f;

  for (int k0 = 0; k0 < K_CONV; k0 += 32) {
    int tap = k0 >> 7, ci0 = k0 & 127;
    int kh = tap / 3, kw = tap - kh * 3;
    #pragma unroll
    for (int g2 = 0; g2 < 2; ++g2) {   // A: 512 granules
      int g = t + g2 * 256, row = g >> 2, qq = g & 3;
      u16x8 d = *(const u16x8*)(wb + row * K_CONV + k0 + qq * 8);
      *(u16x8*)(As + SW(row, qq)) = d;
    }
    {   // B: 256 granules
      int h1 = 2 * oh + kh, w1 = 2 * ow + kw;
      u16x8 d = *(const u16x8*)(yb + ((size_t)h1 * HP_ + w1) * C_ + ci0 + q * 8);
      *(u16x8*)(Bs + SW(pos, q)) = d;
    }
    __syncthreads();
    s16x8 af[4], bf[2];
    #pragma unroll
    for (int i = 0; i < 4; ++i) {
      int r = mh + i * 16 + (l & 15);
      af[i] = *(const s16x8*)(As + SW(r, (l >> 4)));
    }
    #pragma unroll
    for (int j = 0; j < 2; ++j) {
      int r = nh + j * 16 + (l & 15);
      bf[j] = *(const s16x8*)(Bs + SW(r, (l >> 4)));
    }
    #pragma unroll
    for (int i = 0; i < 4; ++i)
      #pragma unroll
      for (int j = 0; j < 2; ++j)
        acc[i][j] = __builtin_amdgcn_mfma_f32_16x16x32_bf16(af[i], bf[j], acc[i][j], 0, 0, 0);
    __syncthreads();
  }

  if (mode == 0) {  // out[b][n][c] via LDS bounce (coalesced u16x8 stores)
    ushort* tb = (ushort*)smem;  // [64 pos][128 co]
    #pragma unroll
    for (int i = 0; i < 4; ++i) {
      int co4 = mh + i * 16 + (l >> 4) * 4;
      float4 bi = *(const float4*)&bias[co4];
      float bia[4] = {bi.x, bi.y, bi.z, bi.w};
      #pragma unroll
      for (int j = 0; j < 2; ++j) {
        int pp = nh + j * 16 + (l & 15);
        #pragma unroll
        for (int r = 0; r < 4; ++r)
          tb[pp * 128 + co4 + r] = f2bf(acc[i][j][r] + bia[r]);
      }
    }
    __syncthreads();
    #pragma unroll
    for (int it = 0; it < 4; ++it) {
      int g = t + it * 256;
      int row = g >> 4, gg = g & 15;
      u16x8 d = *(const u16x8*)(tb + row * 128 + gg * 8);
      *(u16x8*)(out + ((size_t)b * N_ + n0 + row) * C_ + gg * 8) = d;
    }
  } else {          // out[b][c][n] via LDS bounce
    ushort* tb = (ushort*)smem;  // [co][64 pos]
    #pragma unroll
    for (int i = 0; i < 4; ++i) {
      int co4 = mh + i * 16 + (l >> 4) * 4;
      float4 bi = *(const float4*)&bias[co4];
      float bia[4] = {bi.x, bi.y, bi.z, bi.w};
      #pragma unroll
      for (int j = 0; j < 2; ++j) {
        int pp = nh + j * 16 + (l & 15);
        #pragma unroll
        for (int r = 0; r < 4; ++r)
          tb[(co4 + r) * 64 + pp] = f2bf(acc[i][j][r] + bia[r]);
      }
    }
    __syncthreads();
    for (int g = t; g < 1024; g += 256) {
      int co = g >> 3, off = (g & 7) * 8;
      u16x8 d = *(const u16x8*)(tb + co * 64 + off);
      *(u16x8*)(out + ((size_t)b * C_ + co) * N_ + n0 + off) = d;
    }
  }
}

// ---------------- scores: D[n][m] bf16 = sum_c f[n][c]*g[m][c] --------------
__global__ __launch_bounds__(256) void k_scores(const ushort* __restrict__ f,
                                                const ushort* __restrict__ g,
                                                ushort* __restrict__ attn) {
  __shared__ __align__(16) char smem[16384];
  char* As = smem;          // 128 n-rows x 64 B
  char* Bs = smem + 8192;   // 128 m-rows x 64 B
  const int b = blockIdx.z, n0 = blockIdx.y * 128, m0 = blockIdx.x * 128;
  const int t = threadIdx.x, l = t & 63, w = t >> 6;
  const ushort* fb = f + (size_t)b * N_ * C_;
  const ushort* gb = g + (size_t)b * N_ * C_;
  const int a0 = (w & 1) * 64, b0 = (w >> 1) * 64;
  f32x4 acc[4][4];
  #pragma unroll
  for (int i = 0; i < 4; ++i)
    #pragma unroll
    for (int j = 0; j < 4; ++j) acc[i][j] = (f32x4)0.f;

  for (int k0 = 0; k0 < C_; k0 += 32) {
    #pragma unroll
    for (int g2 = 0; g2 < 2; ++g2) {
      int gg = t + g2 * 256, row = gg >> 2, qq = gg & 3;
      *(u16x8*)(As + SW(row, qq)) = *(const u16x8*)(fb + (size_t)(n0 + row) * C_ + k0 + qq * 8);
      *(u16x8*)(Bs + SW(row, qq)) = *(const u16x8*)(gb + (size_t)(m0 + row) * C_ + k0 + qq * 8);
    }
    __syncthreads();
    s16x8 af[4], bf[4];
    #pragma unroll
    for (int i = 0; i < 4; ++i)
      af[i] = *(const s16x8*)(As + SW(a0 + i * 16 + (l & 15), (l >> 4)));
    #pragma unroll
    for (int j = 0; j < 4; ++j)
      bf[j] = *(const s16x8*)(Bs + SW(b0 + j * 16 + (l & 15), (l >> 4)));
    #pragma unroll
    for (int i = 0; i < 4; ++i)
      #pragma unroll
      for (int j = 0; j < 4; ++j)
        acc[i][j] = __builtin_amdgcn_mfma_f32_16x16x32_bf16(af[i], bf[j], acc[i][j], 0, 0, 0);
    __syncthreads();
  }
  // epilogue: bounce through LDS, coalesced u16x8 stores; two n-half passes
  ushort* tb = (ushort*)smem;  // [64 n][128 m]
  #pragma unroll
  for (int p = 0; p < 2; ++p) {
    __syncthreads();
    if ((w & 1) == p) {
      #pragma unroll
      for (int i = 0; i < 4; ++i) {
        #pragma unroll
        for (int j = 0; j < 4; ++j) {
          #pragma unroll
          for (int r = 0; r < 4; ++r) {
            int rowl = i * 16 + (l >> 4) * 4 + r;
            int ml = b0 + j * 16 + (l & 15);
            tb[rowl * 128 + ml] = f2bf(acc[i][j][r]);
          }
        }
      }
    }
    __syncthreads();
    #pragma unroll
    for (int it = 0; it < 4; ++it) {
      int g2 = t + it * 256;
      int row = g2 >> 4, gg = g2 & 15;
      u16x8 d = *(const u16x8*)(tb + row * 128 + gg * 8);
      *(u16x8*)(attn + ((size_t)b * N_ + n0 + p * 64 + row) * N_ + m0 + gg * 8) = d;
    }
  }
}

// ---------------- in-place row softmax (bf16 rows, fp32 internal) -----------
__global__ __launch_bounds__(256) void k_softmax(ushort* __restrict__ attn) {
  ushort* row = attn + (size_t)blockIdx.x * N_;
  const int t = threadIdx.x;
  float v[9];
  float mx = -1e30f;
  #pragma unroll
  for (int i = 0; i < 9; ++i) { v[i] = bf2f(row[t + 256 * i]); mx = fmaxf(mx, v[i]); }
  #pragma unroll
  for (int o = 32; o > 0; o >>= 1) mx = fmaxf(mx, __shfl_xor(mx, o, 64));
  __shared__ float red[4];
  int wv = t >> 6;
  if ((t & 63) == 0) red[wv] = mx;
  __syncthreads();
  mx = fmaxf(fmaxf(red[0], red[1]), fmaxf(red[2], red[3]));
  float sm = 0.f;
  #pragma unroll
  for (int i = 0; i < 9; ++i) { v[i] = __expf(v[i] - mx); sm += v[i]; }
  #pragma unroll
  for (int o = 32; o > 0; o >>= 1) sm += __shfl_xor(sm, o, 64);
  __syncthreads();
  if ((t & 63) == 0) red[wv] = sm;
  __syncthreads();
  sm = red[0] + red[1] + red[2] + red[3];
  float inv = 1.f / sm;
  #pragma unroll
  for (int i = 0; i < 9; ++i) row[t + 256 * i] = f2bf(v[i] * inv);
}

// ---------------- transpose: attnT[b][m][n] = attn[b][n][m] -----------------
__global__ __launch_bounds__(256) void k_transp(const ushort* __restrict__ a,
                                                ushort* __restrict__ at) {
  __shared__ ushort Ls[64][65];
  const int b = blockIdx.z, n0 = blockIdx.y * 64, m0 = blockIdx.x * 64;
  const int t = threadIdx.x, g = t & 7, r0 = t >> 3;  // r0 in [0,32)
  const ushort* ab = a + (size_t)b * N_ * N_;
  ushort* atb = at + (size_t)b * N_ * N_;
  #pragma unroll
  for (int it = 0; it < 2; ++it) {
    int row = r0 + it * 32;  // n-local
    u16x8 d = *(const u16x8*)(ab + (size_t)(n0 + row) * N_ + m0 + g * 8);
    #pragma unroll
    for (int j = 0; j < 8; ++j) Ls[g * 8 + j][row] = d[j];  // Ls[m][n]
  }
  __syncthreads();
  #pragma unroll
  for (int it = 0; it < 2; ++it) {
    int mrow = r0 + it * 32;
    u16x8 o;
    #pragma unroll
    for (int j = 0; j < 8; ++j) o[j] = Ls[mrow][g * 8 + j];
    *(u16x8*)(atb + (size_t)(m0 + mrow) * N_ + n0 + g * 8) = o;
  }
}

// ---------------- sgemm: s[c][m] fp32 = gamma * sum_n h[c][n]*attnT[m][n] ---
__global__ __launch_bounds__(256) void k_sgemm(const ushort* __restrict__ h,
                                               const ushort* __restrict__ attnT,
                                               const float* __restrict__ gammap,
                                               float* __restrict__ s) {
  __shared__ __align__(16) char smem[8192];
  char* As = smem;          // 64 c-rows x 64 B (swizzled)
  char* Bs = smem + 4096;   // 64 m-rows x 64 B (swizzled)
  const int b = blockIdx.z, c0 = blockIdx.y * 64, m0 = blockIdx.x * 64;
  const int t = threadIdx.x, l = t & 63, w = t >> 6;
  const ushort* hb = h + (size_t)b * C_ * N_ + (size_t)c0 * N_;
  const ushort* ab = attnT + (size_t)b * N_ * N_ + (size_t)m0 * N_;
  const int srow = t >> 2, sq = t & 3;
  const int c_off = (w & 1) * 32, m_off = (w >> 1) * 32;
  f32x4 acc[2][2];
  #pragma unroll
  for (int i = 0; i < 2; ++i)
    #pragma unroll
    for (int j = 0; j < 2; ++j) acc[i][j] = (f32x4)0.f;

  for (int k0 = 0; k0 < N_; k0 += 32) {
    *(u16x8*)(As + SW(srow, sq)) = *(const u16x8*)(hb + (size_t)srow * N_ + k0 + sq * 8);
    *(u16x8*)(Bs + SW(srow, sq)) = *(const u16x8*)(ab + (size_t)srow * N_ + k0 + sq * 8);
    __syncthreads();
    s16x8 af[2], bf[2];
    #pragma unroll
    for (int i = 0; i < 2; ++i)
      af[i] = *(const s16x8*)(As + SW(c_off + i * 16 + (l & 15), (l >> 4)));
    #pragma unroll
    for (int j = 0; j < 2; ++j)
      bf[j] = *(const s16x8*)(Bs + SW(m_off + j * 16 + (l & 15), (l >> 4)));
    #pragma unroll
    for (int i = 0; i < 2; ++i)
      #pragma unroll
      for (int j = 0; j < 2; ++j)
        acc[i][j] = __builtin_amdgcn_mfma_f32_16x16x32_bf16(af[i], bf[j], acc[i][j], 0, 0, 0);
    __syncthreads();
  }
  const float gv = gammap[0];
  #pragma unroll
  for (int i = 0; i < 2; ++i) {
    int c4 = c0 + c_off + i * 16 + (l >> 4) * 4;
    #pragma unroll
    for (int j = 0; j < 2; ++j) {
      int m = m0 + m_off + j * 16 + (l & 15);
      #pragma unroll
      for (int r = 0; r < 4; ++r)
        s[((size_t)b * C_ + c4 + r) * N_ + m] = gv * acc[i][j][r];
    }
  }
}

// ---------------- ws = relu(mean_m s) ---------------------------------------
__global__ __launch_bounds__(256) void k_means(const float* __restrict__ s,
                                               float* __restrict__ wcat) {
  int bc = blockIdx.x;
  const float* p = s + (size_t)bc * N_;
  float sm = 0.f;
  for (int i = threadIdx.x; i < N_; i += 256) sm += p[i];
  sm = block_reduce_sum_256(sm);
  if (threadIdx.x == 0) {
    int b = bc >> 7, c = bc & 127;
    wcat[b * 256 + 128 + c] = fmaxf(sm * (1.f / N_), 0.f);
  }
}

// ---------------- SE MLP: 256 -> 42 (relu) -> 128 ---------------------------
__global__ __launch_bounds__(128) void k_se(const float* __restrict__ wcat,
                                            const float* __restrict__ cw,
                                            const float* __restrict__ cb,
                                            const float* __restrict__ uw,
                                            const float* __restrict__ ub,
                                            float* __restrict__ se) {
  const int b = blockIdx.x, t = threadIdx.x;
  __shared__ float wc[256];
  __shared__ float s1[42];
  wc[t] = wcat[b * 256 + t];
  wc[128 + t] = wcat[b * 256 + 128 + t];
  __syncthreads();
  if (t < 42) {
    float a = cb[t];
    const float* r = cw + (size_t)t * 256;
    for (int k = 0; k < 256; ++k) a += wc[k] * r[k];
    s1[t] = fmaxf(a, 0.f);
  }
  __syncthreads();
  {
    float a = ub[t];
    const float* r = uw + (size_t)t * 42;
    for (int j = 0; j < 42; ++j) a += s1[j] * r[j];
    se[b * 128 + t] = a;
  }
}

// ---------------- out = (avgpool2x2(x) + s) * (1 + se) ----------------------
__global__ __launch_bounds__(256) void k_final(const float* __restrict__ x,
                                               const float* __restrict__ s,
                                               const float* __restrict__ se,
                                               float* __restrict__ out) {
  int idx = blockIdx.x * 256 + threadIdx.x;
  if (idx >= TOT_OUT) return;
  int m  = idx % N_;
  int bc = idx / N_;
  int oh = m / HO_, ow = m - oh * HO_;
  const float* xp = x + (size_t)bc * PLANE_IN;
  int ih = oh * 2, iw = ow * 2;
  float l = 0.25f * (xp[ih * W_ + iw] + xp[ih * W_ + iw + 1] +
                     xp[(ih + 1) * W_ + iw] + xp[(ih + 1) * W_ + iw + 1]);
  out[idx] = (l + s[idx]) * (1.f + se[bc]);
}

extern "C" void kernel_launch(void* const* d_in, const int* in_sizes, int n_in,
                              void* d_out, int out_size, void* d_ws, size_t ws_size,
                              hipStream_t stream) {
  (void)in_sizes; (void)n_in; (void)out_size; (void)ws_size;
  const float* x    = (const float*)d_in[0];
  const float* bnw[3] = {(const float*)d_in[1],  (const float*)d_in[7],  (const float*)d_in[13]};
  const float* bnb[3] = {(const float*)d_in[2],  (const float*)d_in[8],  (const float*)d_in[14]};
  const float* bnm[3] = {(const float*)d_in[3],  (const float*)d_in[9],  (const float*)d_in[15]};
  const float* bnv[3] = {(const float*)d_in[4],  (const float*)d_in[10], (const float*)d_in[16]};
  const float* cw_[3] = {(const float*)d_in[5],  (const float*)d_in[11], (const float*)d_in[17]};
  const float* cbb[3] = {(const float*)d_in[6],  (const float*)d_in[12], (const float*)d_in[18]};
  const float* secw = (const float*)d_in[19];
  const float* secb = (const float*)d_in[20];
  const float* seuw = (const float*)d_in[21];
  const float* seub = (const float*)d_in[22];
  const float* gamma = (const float*)d_in[23];
  float* out = (float*)d_out;

  char* ws = (char*)d_ws;
  size_t off = 0;
  auto alloc = [&](size_t bytes) -> char* {
    char* p = ws + off;
    off = (off + bytes + 255) & ~(size_t)255;
    return p;
  };
  ushort* attn  = (ushort*)alloc((size_t)B_ * N_ * N_ * 2);      // 85 MB bf16
  ushort* attnT = (ushort*)alloc((size_t)B_ * N_ * N_ * 2);      // 85 MB bf16
  ushort* yp[3];
  for (int p = 0; p < 3; ++p) yp[p] = (ushort*)alloc((size_t)B_ * HP_ * HP_ * C_ * 2);
  ushort* wb[3];
  for (int p = 0; p < 3; ++p) wb[p] = (ushort*)alloc((size_t)C_ * K_CONV * 2);
  ushort* fbuf = (ushort*)alloc((size_t)B_ * N_ * C_ * 2);       // [b][n][c]
  ushort* gbuf = (ushort*)alloc((size_t)B_ * N_ * C_ * 2);       // [b][n][c]
  ushort* hbuf = (ushort*)alloc((size_t)B_ * C_ * N_ * 2);       // [b][c][n]
  float*  sbuf = (float*)alloc((size_t)B_ * C_ * N_ * 4);        // [b][c][n]
  float*  wcat = (float*)alloc(B_ * 256 * 4);
  float*  sebuf = (float*)alloc(B_ * 128 * 4);
  float*  pinv  = (float*)alloc(3 * 128 * 4);
  float*  pbeta = (float*)alloc(3 * 128 * 4);

  for (int p = 0; p < 3; ++p)
    k_prep<<<1, 128, 0, stream>>>(bnw[p], bnb[p], bnm[p], bnv[p], pinv + p * 128, pbeta + p * 128);
  for (int p = 0; p < 3; ++p)
    k_prep_w<<<(C_ * K_CONV + 255) / 256, 256, 0, stream>>>(cw_[p], wb[p]);
  k_prep_y<<<dim3(HP_, B_), 256, 0, stream>>>(x, pinv, pbeta, yp[0], yp[1], yp[2]);

  k_meanx<<<B_ * C_, 256, 0, stream>>>(x, wcat);

  k_conv<<<dim3(N_ / 64, 1, B_), 256, 0, stream>>>(yp[0], wb[0], cbb[0], fbuf, 0);
  k_conv<<<dim3(N_ / 64, 1, B_), 256, 0, stream>>>(yp[1], wb[1], cbb[1], gbuf, 0);
  k_conv<<<dim3(N_ / 64, 1, B_), 256, 0, stream>>>(yp[2], wb[2], cbb[2], hbuf, 1);

  k_scores<<<dim3(N_ / 128, N_ / 128, B_), 256, 0, stream>>>(fbuf, gbuf, attn);
  k_softmax<<<B_ * N_, 256, 0, stream>>>(attn);
  k_transp<<<dim3(N_ / 64, N_ / 64, B_), 256, 0, stream>>>(attn, attnT);
  k_sgemm<<<dim3(N_ / 64, 2, B_), 256, 0, stream>>>(hbuf, attnT, gamma, sbuf);

  k_means<<<B_ * C_, 256, 0, stream>>>(sbuf, wcat);
  k_se<<<B_, 128, 0, stream>>>(wcat, secw, secb, seuw, seub, sebuf);

  k_final<<<(TOT_OUT + 255) / 256, 256, 0, stream>>>(x, sbuf, sebuf, out);
}